// Round 9
// baseline (295.650 us; speedup 1.0000x reference)
//
#include <hip/hip_runtime.h>
#include <hip/hip_bf16.h>

// GCN v19 — v18 base (proven 274.7 us) + fused gather+MFMA (k_gm) + k_h2 merge.
//   r18 accounting: gathers 101 us (at the 3.5 TB/s random-row wall); the
//   other 173.6 us across 8 dispatches models to only ~85 us of work ->
//   dispatch ramp/drain bubbles dominate the build phase. v19 cuts
//   10 -> 7 dispatches: (a) k_gm fuses gather + matvec — 4-wave block
//   gathers 16 nodes into padded LDS (stride 72 bf16, <=2-way bank alias),
//   sync, each wave MFMAs one 16-col n-tile and stores; deletes k_mat x2
//   and the 12.8 MB a-buffer round-trip per layer. (b) k_hd+k_hc re-merged
//   (v16 union-LDS pattern at 1024 threads). Build kernels otherwise
//   byte-identical to v18.

#define FDIM 64
#define NPART 4
#define GPB 64
#define NB 256
#define BW 512
#define MAXP 1024
#define GPLIN 1024

typedef __hip_bfloat16 bf16;
typedef short v8s __attribute__((ext_vector_type(8)));
typedef float v4f __attribute__((ext_vector_type(4)));

static __device__ __forceinline__ float ulo2f(unsigned u) {
    union { unsigned x; float f; } v; v.x = u << 16; return v.f;
}
static __device__ __forceinline__ float uhi2f(unsigned u) {
    union { unsigned x; float f; } v; v.x = u & 0xFFFF0000u; return v.f;
}
static __device__ __forceinline__ unsigned f2bu(float f) {
    bf16 b = __float2bfloat16(f);
    return (unsigned)(*(unsigned short*)&b);
}

// --- dispatch 1: deg u8 partial hist (b < NPART*GPB) ∥ col coarse hist ---
__global__ __launch_bounds__(1024)
void k_h2(const int* __restrict__ row, const int* __restrict__ col,
          unsigned* __restrict__ part, int* __restrict__ M,
          int E, int n, int psize, int psize4, int P, int CH) {
    __shared__ unsigned sm[6256];
    int t = threadIdx.x, b = blockIdx.x;
    if (b < NPART * GPB) {
        int p = b >> 6, g = b & 63;
        int base = p * psize;
        int lim = n - base; if (lim > psize) lim = psize;
        int lim4 = (lim + 3) >> 2;
        for (int i = t; i < lim4; i += 1024) sm[i] = 0u;
        __syncthreads();
        // E % 4 == 0: every int4 batch is in-bounds and 16B-aligned.
        for (int e = (g * 1024 + t) * 4; e < E; e += GPB * 4096) {
            int4 r4 = *(const int4*)&row[e];
            int r0 = r4.x - base, r1 = r4.y - base, r2 = r4.z - base, r3 = r4.w - base;
            if ((unsigned)r0 < (unsigned)lim) atomicAdd(&sm[r0 >> 2], 1u << ((r0 & 3) * 8));
            if ((unsigned)r1 < (unsigned)lim) atomicAdd(&sm[r1 >> 2], 1u << ((r1 & 3) * 8));
            if ((unsigned)r2 < (unsigned)lim) atomicAdd(&sm[r2 >> 2], 1u << ((r2 & 3) * 8));
            if ((unsigned)r3 < (unsigned)lim) atomicAdd(&sm[r3 >> 2], 1u << ((r3 & 3) * 8));
        }
        __syncthreads();
        unsigned* dst = part + ((size_t)p * GPB + g) * psize4;
        for (int i = t; i < lim4; i += 1024) dst[i] = sm[i];
    } else {
        int cb = b - NPART * GPB;
        int* h = (int*)sm;
        for (int i = t; i < P; i += 1024) h[i] = 0;
        __syncthreads();
        int s = cb * CH, e = min(s + CH, E);   // multiples of 4 (CH % 4 == 0)
        for (int i = s + t * 4; i < e; i += 4096) {
            int4 c4 = *(const int4*)&col[i];
            atomicAdd(&h[c4.x >> 9], 1);
            atomicAdd(&h[c4.y >> 9], 1);
            atomicAdd(&h[c4.z >> 9], 1);
            atomicAdd(&h[c4.w >> 9], 1);
        }
        __syncthreads();
        for (int p = t; p < P; p += 1024) M[p * NB + cb] = h[p];
    }
}

// --- dis from u8 partials (4 nodes/thread) ∥ scan pass 1 ---
__global__ void k_ds1(const unsigned* __restrict__ part, float* __restrict__ dis,
                      int* __restrict__ M, int* __restrict__ bsum,
                      int n, int psize4, int ndis4, int P) {
    __shared__ int sc[256];
    int t = threadIdx.x, b = blockIdx.x;
    if (b < ndis4) {
        int i4 = b * 256 + t;
        int i = i4 * 4;
        if (i >= n) return;
        int p = i4 / psize4, loc = i4 - p * psize4;
        const unsigned* src = part + (size_t)p * GPB * psize4 + loc;
        unsigned s0 = 0, s1 = 0, s2 = 0, s3 = 0;
        #pragma unroll 8
        for (int g = 0; g < GPB; ++g) {
            unsigned u = src[(size_t)g * psize4];
            s0 += u & 255u; s1 += (u >> 8) & 255u;
            s2 += (u >> 16) & 255u; s3 += u >> 24;
        }
        dis[i] = rsqrtf((float)s0 + 1.0f);
        if (i + 1 < n) dis[i + 1] = rsqrtf((float)s1 + 1.0f);
        if (i + 2 < n) dis[i + 2] = rsqrtf((float)s2 + 1.0f);
        if (i + 3 < n) dis[i + 3] = rsqrtf((float)s3 + 1.0f);
    } else {
        int sb = b - ndis4;
        int i = sb * 256 + t;
        int v = M[i];
        sc[t] = v;
        __syncthreads();
        for (int d = 1; d < 256; d <<= 1) {
            int u = (t >= d) ? sc[t - d] : 0;
            __syncthreads(); sc[t] += u; __syncthreads();
        }
        M[i] = sc[t] - v;
        if (t == 255) bsum[sb] = sc[255];
    }
}

// --- coarse scatter, 1024 threads, int4 sweep (scan guarded to t<256) ---
__global__ __launch_bounds__(1024)
void k_csc(const int* __restrict__ row, const int* __restrict__ col,
           const int* __restrict__ M, const int* __restrict__ bsum,
           int* __restrict__ s4, int E, int CH, int P) {
    __shared__ int sc[256];
    __shared__ int bs[256];
    __shared__ int cur[MAXP];
    int t = threadIdx.x, b = blockIdx.x;
    if (t < 256) { int v = (t < P) ? bsum[t] : 0; sc[t] = v; bs[t] = v; }
    __syncthreads();
    for (int d = 1; d < 256; d <<= 1) {
        int u = (t < 256 && t >= d) ? sc[t - d] : 0;
        __syncthreads();
        if (t < 256) sc[t] += u;
        __syncthreads();
    }
    if (t < 256) bs[t] = sc[t] - bs[t];
    __syncthreads();
    for (int p = t; p < P; p += 1024) cur[p] = bs[p] + M[p * NB + b];
    __syncthreads();
    int s = b * CH, e = min(s + CH, E);   // multiples of 4
    for (int i = s + t * 4; i < e; i += 4096) {
        int4 r4 = *(const int4*)&row[i];
        int4 c4 = *(const int4*)&col[i];
        int p0 = atomicAdd(&cur[c4.x >> 9], 1);
        s4[p0] = (r4.x << 9) | (c4.x & 511);
        int p1 = atomicAdd(&cur[c4.y >> 9], 1);
        s4[p1] = (r4.y << 9) | (c4.y & 511);
        int p2 = atomicAdd(&cur[c4.z >> 9], 1);
        s4[p2] = (r4.z << 9) | (c4.z & 511);
        int p3 = atomicAdd(&cur[c4.w >> 9], 1);
        s4[p3] = (r4.w << 9) | (c4.w & 511);
    }
}

// --- fine counting sort, 1024 threads (scans guarded to t<256) ---
__global__ __launch_bounds__(1024)
void k_fsort(const int* __restrict__ s4, const int* __restrict__ bsum,
             int* __restrict__ rows4, int* __restrict__ off,
             int n, int E, int P) {
    __shared__ int sc[256];
    __shared__ int bs[256];
    __shared__ int hist[BW];
    __shared__ int loff[BW];
    __shared__ int tmp[256];
    int t = threadIdx.x, b = blockIdx.x;
    if (t < 256) { int v = (t < P) ? bsum[t] : 0; sc[t] = v; bs[t] = v; }
    __syncthreads();
    for (int d = 1; d < 256; d <<= 1) {
        int u = (t < 256 && t >= d) ? sc[t - d] : 0;
        __syncthreads();
        if (t < 256) sc[t] += u;
        __syncthreads();
    }
    if (t < 256) bs[t] = sc[t] - bs[t];
    __syncthreads();
    int gs = bs[b];
    int ge = gs + bsum[b];
    int c0 = b << 9;
    int lim = n - c0; if (lim > BW) lim = BW;
    for (int i = t; i < BW; i += 1024) hist[i] = 0;
    __syncthreads();
    for (int i = gs + t; i < ge; i += 1024)
        atomicAdd(&hist[s4[i] & 511], 1);
    __syncthreads();
    int s0 = 0, s1v = 0, ps = 0;
    if (t < 256) {
        s0 = hist[2 * t]; s1v = hist[2 * t + 1];
        ps = s0 + s1v;
        tmp[t] = ps;
    }
    __syncthreads();
    for (int d = 1; d < 256; d <<= 1) {
        int u = (t < 256 && t >= d) ? tmp[t - d] : 0;
        __syncthreads();
        if (t < 256) tmp[t] += u;
        __syncthreads();
    }
    if (t < 256) {
        int ex = tmp[t] - ps;
        loff[2 * t] = ex;
        loff[2 * t + 1] = ex + s0;
    }
    __syncthreads();
    for (int i = t; i < lim; i += 1024) off[c0 + i] = gs + loff[i];
    if (b == P - 1 && t == 0) off[n] = E;
    __syncthreads();
    for (int i = gs + t; i < ge; i += 1024) {
        int v2 = s4[i];
        int pos = gs + atomicAdd(&loff[v2 & 511], 1);
        rows4[pos] = v2 >> 9;
    }
}

// --- linear layer 1: g1 = bf16(dis * (concat(x,feat)@W1 + b1)) ---
__global__ __launch_bounds__(256, 4)
void k_linc(const float* __restrict__ x, const float* __restrict__ feat,
            const float* __restrict__ W, const float* __restrict__ bvec,
            const float* __restrict__ dis, bf16* __restrict__ g1, int n) {
    __shared__ float sIn[4][FDIM];
    int t = threadIdx.x;
    int local = t >> 6, j = t & 63;
    float Wreg[FDIM];
    #pragma unroll
    for (int k = 0; k < FDIM; ++k) Wreg[k] = W[k * FDIM + j];
    float bj = bvec[j];
    int gw = blockIdx.x * 4 + local;
    int nwl = GPLIN * 4;
    for (int w = gw; w < n; w += nwl) {
        sIn[local][j] = (j < 32) ? x[(size_t)w * 32 + j]
                                 : feat[(size_t)w * 32 + (j - 32)];
        __threadfence_block();
        float o = bj;
        #pragma unroll
        for (int k4 = 0; k4 < 16; ++k4) {
            float4 h4 = *(const float4*)&sIn[local][k4 * 4];
            o = fmaf(h4.x, Wreg[4 * k4 + 0], o);
            o = fmaf(h4.y, Wreg[4 * k4 + 1], o);
            o = fmaf(h4.z, Wreg[4 * k4 + 2], o);
            o = fmaf(h4.w, Wreg[4 * k4 + 3], o);
        }
        g1[(size_t)w * FDIM + j] = __float2bfloat16(dis[w] * o);
        __threadfence_block();
    }
}

// --- fused gather + MFMA matvec ---
// Per 16-node tile: 4 waves each gather 4 consecutive nodes (dual-edge
// proven form: half-wave edge parity, ushort2/lane = 256 B per instr,
// 8-deep unroll) writing relu(dis*(self+sum)) bf16 rows into padded LDS
// (stride 72 bf16 = 36 u32 -> <=2-way bank alias, free). Sync, then wave
// wv MFMAs n-tile wv (2 x mfma 16x16x32) and stores o+b directly.
// FINAL ? relu(o) f32 : bf16(dis*o). Deletes k_mat and the a-buffer.
template <bool FINAL>
__global__ __launch_bounds__(256, 4)
void k_gm(const int* __restrict__ rows4, const int* __restrict__ off,
          const float* __restrict__ dis, const bf16* __restrict__ g,
          const float* __restrict__ W, const float* __restrict__ bvec,
          void* __restrict__ outp, int n) {
    __shared__ __align__(16) bf16 sWt[FDIM * FDIM];   // Wt[n][k]
    __shared__ __align__(16) unsigned sA[16 * 36];    // 16 rows x (32 u32 + 4 pad)
    int t = threadIdx.x;
    for (int idx = t; idx < FDIM * FDIM; idx += 256) {
        int kk = idx >> 6, nn = idx & 63;
        sWt[nn * FDIM + kk] = __float2bfloat16(W[idx]);
    }
    __syncthreads();
    int wv = t >> 6, lane = t & 63;
    int quad = lane >> 4, l15 = lane & 15;
    int h = lane >> 5, j2 = lane & 31;
    // B-fragments for this wave's n-tile (nt = wv); proven k_mat layout.
    v8s bfr0 = *(const v8s*)&sWt[(wv * 16 + l15) * FDIM + quad * 8];
    v8s bfr1 = *(const v8s*)&sWt[(wv * 16 + l15) * FDIM + 32 + quad * 8];
    float bj = bvec[wv * 16 + l15];
    const unsigned* g32 = (const unsigned*)g;
    const bf16* sAb = (const bf16*)sA;
    int ntiles = (n + 15) >> 4;
    for (int tile = blockIdx.x; tile < ntiles; tile += gridDim.x) {
        int m0 = tile << 4;
        // ---- gather phase: wave wv fills LDS rows wv*4 .. wv*4+3 ----
        #pragma unroll
        for (int i = 0; i < 4; ++i) {
            int w = m0 + wv * 4 + i;
            if (w >= n) break;                 // uniform per wave
            float acc0 = 0.0f, acc1 = 0.0f;
            int s = off[w], e = off[w + 1];
            int k = s;
            for (; k + 16 <= e; k += 16) {
                #pragma unroll
                for (int u = 0; u < 8; ++u) {
                    int r = rows4[k + 2 * u + h];
                    unsigned uu = g32[(size_t)r * 32 + j2];
                    acc0 += ulo2f(uu);
                    acc1 += uhi2f(uu);
                }
            }
            if (k < e) {
                #pragma unroll
                for (int u = 0; u < 8; ++u) {
                    int idx = k + 2 * u + h;
                    int r = rows4[min(idx, e - 1)];
                    unsigned uu = g32[(size_t)r * 32 + j2];
                    float wg = (idx < e) ? 1.0f : 0.0f;
                    acc0 = fmaf(wg, ulo2f(uu), acc0);
                    acc1 = fmaf(wg, uhi2f(uu), acc1);
                }
            }
            acc0 += __shfl_xor(acc0, 32, 64);
            acc1 += __shfl_xor(acc1, 32, 64);
            if (h == 0) {
                unsigned su = g32[(size_t)w * 32 + j2];   // self loop
                float dv = dis[w];
                float v0 = fmaxf(dv * (acc0 + ulo2f(su)), 0.0f);
                float v1 = fmaxf(dv * (acc1 + uhi2f(su)), 0.0f);
                sA[(wv * 4 + i) * 36 + j2] = f2bu(v0) | (f2bu(v1) << 16);
            }
        }
        __syncthreads();
        // ---- mat phase: wave wv computes n-tile wv for all 16 rows ----
        v8s af0 = *(const v8s*)&sAb[l15 * 72 + quad * 8];
        v8s af1 = *(const v8s*)&sAb[l15 * 72 + 32 + quad * 8];
        v4f acc = (v4f){0.f, 0.f, 0.f, 0.f};
        acc = __builtin_amdgcn_mfma_f32_16x16x32_bf16(af0, bfr0, acc, 0, 0, 0);
        acc = __builtin_amdgcn_mfma_f32_16x16x32_bf16(af1, bfr1, acc, 0, 0, 0);
        #pragma unroll
        for (int r = 0; r < 4; ++r) {
            int node = m0 + quad * 4 + r;
            if (node >= n) continue;
            int j = wv * 16 + l15;
            float o = acc[r] + bj;
            if (FINAL) {
                ((float*)outp)[(size_t)node * FDIM + j] = fmaxf(o, 0.0f);
            } else {
                ((bf16*)outp)[(size_t)node * FDIM + j] =
                    __float2bfloat16(dis[node] * o);
            }
        }
        __syncthreads();   // protect sA before next tile's gather writes
    }
}

extern "C" void kernel_launch(void* const* d_in, const int* in_sizes, int n_in,
                              void* d_out, int out_size, void* d_ws, size_t ws_size,
                              hipStream_t stream) {
    const float* x    = (const float*)d_in[0];
    const float* feat = (const float*)d_in[1];
    const int*   ei   = (const int*)d_in[2];
    const float* W1   = (const float*)d_in[3];
    const float* b1   = (const float*)d_in[4];
    const float* W2   = (const float*)d_in[5];
    const float* b2   = (const float*)d_in[6];
    const float* Wfc  = (const float*)d_in[7];
    const float* bfc  = (const float*)d_in[8];
    float* out = (float*)d_out;

    const int n = in_sizes[0] / 32;   // 100000
    const int E = in_sizes[2] / 2;    // 1600000 (multiple of 4)
    const int* row = ei;
    const int* col = ei + E;

    const int psize = (((n + NPART - 1) / NPART) + 3) & ~3;   // 25000
    const int psize4 = psize >> 2;                            // 6250
    const int P  = (n + BW - 1) / BW;                         // 196
    const int CH = (((E + NB - 1) / NB) + 3) & ~3;            // 6252 (x4 aligned)
    const int total = P * NB;                                 // 50176
    const int ndis4 = (((n + 3) / 4) + 255) / 256;            // 98

    // ws: off[n+1] | dis[n] | M[total] | bsum[256] | s4[E] | rows4[E]
    //     | (16B-aligned) bufA(bf16 64n) | bufB(bf16 64n)
    // part (NPART*GPB*psize4 u32 = 6.4 MB) aliases bufA (consumed in k_ds1
    // before k_linc writes g1 into bufA).
    int*   off  = (int*)d_ws;
    float* dis  = (float*)(off + (size_t)n + 1);
    int*   M    = (int*)(dis + n);
    int*   bsum = M + (size_t)total;
    int*   s4    = bsum + 256;
    int*   rows4 = s4 + E;
    size_t co = (size_t)(rows4 + E - (int*)d_ws);
    co = (co + 3) & ~(size_t)3;                  // 16B align for v8s loads
    bf16*  bufA  = (bf16*)((int*)d_ws + co);
    bf16*  bufB  = bufA + (size_t)n * FDIM;
    unsigned* part = (unsigned*)bufA;

    k_h2<<<NPART * GPB + NB, 1024, 0, stream>>>(row, col, part, M, E, n,
                                                psize, psize4, P, CH);
    k_ds1<<<ndis4 + P, 256, 0, stream>>>(part, dis, M, bsum, n, psize4, ndis4, P);
    k_csc<<<NB, 1024, 0, stream>>>(row, col, M, bsum, s4, E, CH, P);
    k_fsort<<<P, 1024, 0, stream>>>(s4, bsum, rows4, off, n, E, P);
    k_linc<<<GPLIN, 256, 0, stream>>>(x, feat, W1, b1, dis, bufA, n);
    // layer 2 fused: g2 = bf16(dis*(gather(g1)@W2+b2))
    k_gm<false><<<2048, 256, 0, stream>>>(rows4, off, dis, bufA, W2, b2, bufB, n);
    // fc fused: out = relu(gather(g2)@Wfc+bfc)
    k_gm<true><<<2048, 256, 0, stream>>>(rows4, off, dis, bufB, Wfc, bfc, out, n);
}